// Round 2
// baseline (232.273 us; speedup 1.0000x reference)
//
#include <hip/hip_runtime.h>

// Problem constants (reference: B=32, S=4096, D=256, float32)
constexpr int S_LEN = 4096;
constexpr int D_DIM = 256;
constexpr int ROWS_PER_BLOCK = 16;                       // one wave per row
constexpr int BLOCK_THREADS  = ROWS_PER_BLOCK * 64;      // 1024
constexpr int BLOCKS_PER_BATCH = S_LEN / ROWS_PER_BLOCK; // 256

// ---------------------------------------------------------------------------
// Fused single-pass stream compaction.
// Each block owns 16 consecutive timestep rows of one batch. It recomputes the
// batch-row's full exclusive prefix of keep_mask in-block (16 KiB mask read,
// L2-resident across the 256 blocks of a batch), then each of its 16 waves
// moves one 1 KiB row:
//   kept row t    -> out row pos[t]                (copy)
//   dropped row t -> out row cnt + (t - pos[t])    (zeros)
// Every output row is written exactly once -> no memset pass needed.
// ---------------------------------------------------------------------------
__global__ __launch_bounds__(BLOCK_THREADS)
void fused_compact_kernel(const float* __restrict__ x,
                          const int* __restrict__ mask,
                          float* __restrict__ out) {
    const int b   = blockIdx.x / BLOCKS_PER_BATCH;
    const int blk = blockIdx.x % BLOCKS_PER_BATCH;
    const int t0  = blk * ROWS_PER_BLOCK;

    __shared__ int wtot[16];              // per-wave totals (16 waves)
    __shared__ int spos[ROWS_PER_BLOCK];  // exclusive prefix at this block's rows
    __shared__ int skeep[ROWS_PER_BLOCK]; // keep bit at this block's rows

    const int tid  = threadIdx.x;   // 0..1023
    const int lane = tid & 63;
    const int wid  = tid >> 6;      // 0..15

    // --- full-row scan: each thread owns 4 mask elements (1024*4 = 4096) ---
    const int e0 = tid * 4;
    int4 m = *reinterpret_cast<const int4*>(mask + b * S_LEN + e0);
    int v[4] = {m.x, m.y, m.z, m.w};
    const int tot = v[0] + v[1] + v[2] + v[3];

    // wave-64 inclusive scan of per-thread totals
    int scan = tot;
#pragma unroll
    for (int off = 1; off < 64; off <<= 1) {
        int n = __shfl_up(scan, off, 64);
        if (lane >= off) scan += n;
    }
    if (lane == 63) wtot[wid] = scan;
    __syncthreads();

    int wexcl = 0, cnt = 0;
#pragma unroll
    for (int i = 0; i < 16; ++i) {
        int w = wtot[i];
        if (i < wid) wexcl += w;
        cnt += w;
    }

    // exclusive prefix for this thread's first element
    int excl = wexcl + (scan - tot);

    // publish pos/keep for the 16 rows this block owns
#pragma unroll
    for (int i = 0; i < 4; ++i) {
        int r = (e0 + i) - t0;
        if ((unsigned)r < (unsigned)ROWS_PER_BLOCK) {
            spos[r]  = excl;
            skeep[r] = v[i];
        }
        excl += v[i];
    }
    __syncthreads();

    // --- one wave per row: move 1 KiB as 64 lanes x float4 ---
    const int t    = t0 + wid;
    const int keep = skeep[wid];
    const int p    = spos[wid];
    const int orow = keep ? p : (cnt + (t - p));

    const size_t in_off  = ((size_t)b * S_LEN + t)    * D_DIM;
    const size_t out_off = ((size_t)b * S_LEN + orow) * D_DIM;

    float4 val = make_float4(0.f, 0.f, 0.f, 0.f);
    if (keep) val = reinterpret_cast<const float4*>(x + in_off)[lane];
    reinterpret_cast<float4*>(out + out_off)[lane] = val;
}

// ---------------------------------------------------------------------------
extern "C" void kernel_launch(void* const* d_in, const int* in_sizes, int n_in,
                              void* d_out, int out_size, void* d_ws, size_t ws_size,
                              hipStream_t stream) {
    const float* x    = (const float*)d_in[0];
    const int*   mask = (const int*)d_in[1];
    float*       out  = (float*)d_out;

    const int B = in_sizes[1] / S_LEN;   // 32
    const int grid = B * BLOCKS_PER_BATCH;

    fused_compact_kernel<<<grid, BLOCK_THREADS, 0, stream>>>(x, mask, out);
}

// Round 4
// 221.780 us; speedup vs baseline: 1.0473x; 1.0473x over previous
//
#include <hip/hip_runtime.h>

// Problem constants (reference: B=32, S=4096, D=256, float32)
constexpr int S_LEN = 4096;
constexpr int D_DIM = 256;

// ---------------------------------------------------------------------------
// Kernel 1: per-batch scan producing a pre-encoded output-row index.
//   orow_enc[b][t] =  pos[t]                 if keep   (>= 0)
//                  =  ~(cnt + (t - pos[t]))  if drop   (< 0)
// One block (1024 threads) per batch row; each thread owns 4 mask elements.
// ---------------------------------------------------------------------------
__global__ __launch_bounds__(1024)
void scan_kernel(const int* __restrict__ mask,
                 int* __restrict__ orow_enc) {
    const int b   = blockIdx.x;
    const int tid = threadIdx.x;           // 0..1023
    const int lane = tid & 63;
    const int wid  = tid >> 6;             // 0..15
    __shared__ int wtot[16];

    const int base = b * S_LEN + tid * 4;
    int4 m = *reinterpret_cast<const int4*>(mask + base);
    int v[4] = {m.x, m.y, m.z, m.w};
    const int tot = v[0] + v[1] + v[2] + v[3];

    // wave-64 inclusive scan of per-thread totals
    int scan = tot;
#pragma unroll
    for (int off = 1; off < 64; off <<= 1) {
        int n = __shfl_up(scan, off, 64);
        if (lane >= off) scan += n;
    }
    if (lane == 63) wtot[wid] = scan;
    __syncthreads();

    int wexcl = 0, cnt = 0;
#pragma unroll
    for (int i = 0; i < 16; ++i) {
        int w = wtot[i];
        if (i < wid) wexcl += w;
        cnt += w;
    }

    // exclusive prefix at this thread's first element
    int excl = wexcl + (scan - tot);

    int4 e;
    int t = tid * 4;
    e.x = v[0] ? excl : ~(cnt + (t + 0 - excl)); excl += v[0];
    e.y = v[1] ? excl : ~(cnt + (t + 1 - excl)); excl += v[1];
    e.z = v[2] ? excl : ~(cnt + (t + 2 - excl)); excl += v[2];
    e.w = v[3] ? excl : ~(cnt + (t + 3 - excl));
    *reinterpret_cast<int4*>(orow_enc + base) = e;
}

// ---------------------------------------------------------------------------
// Kernel 2: scatter. One wave per timestep row; 64 lanes x float4 = 1 KiB row.
// Per wave: 1 broadcast int load + (kept ? 1 float4 load : 0) + 1 float4 store.
// Every output row is written exactly once -> no memset pass needed.
// ---------------------------------------------------------------------------
__global__ __launch_bounds__(512)
void scatter_kernel(const float* __restrict__ x,
                    const int* __restrict__ orow_enc,
                    float* __restrict__ out) {
    const int lane = threadIdx.x & 63;
    const int w    = blockIdx.x * 8 + (threadIdx.x >> 6);  // global wave/row id
    const int b = w >> 12;                                 // w / 4096
    const int t = w & (S_LEN - 1);

    const int e    = orow_enc[w];          // broadcast load (all lanes same addr)
    const bool keep = (e >= 0);
    const int orow  = keep ? e : ~e;

    const size_t in_off  = ((size_t)b * S_LEN + t)    * D_DIM;
    const size_t out_off = ((size_t)b * S_LEN + orow) * D_DIM;

    float4 val = make_float4(0.f, 0.f, 0.f, 0.f);
    if (keep) val = reinterpret_cast<const float4*>(x + in_off)[lane];
    reinterpret_cast<float4*>(out + out_off)[lane] = val;
}

// ---------------------------------------------------------------------------
extern "C" void kernel_launch(void* const* d_in, const int* in_sizes, int n_in,
                              void* d_out, int out_size, void* d_ws, size_t ws_size,
                              hipStream_t stream) {
    const float* x    = (const float*)d_in[0];
    const int*   mask = (const int*)d_in[1];
    float*       out  = (float*)d_out;

    const int B = in_sizes[1] / S_LEN;     // 32

    int* orow_enc = (int*)d_ws;            // B*S ints = 512 KiB

    scan_kernel<<<B, 1024, 0, stream>>>(mask, orow_enc);

    const int rows = B * S_LEN;            // one wave per row, 8 waves per block
    scatter_kernel<<<rows / 8, 512, 0, stream>>>(x, orow_enc, out);
}